// Round 1
// baseline (1300.218 us; speedup 1.0000x reference)
//
#include <hip/hip_runtime.h>
#include <hip/hip_bf16.h>

#define CCH 256
#define NSEQ 2048
#define BATCH 8

typedef __hip_bfloat16 bf16;
typedef __hip_bfloat162 bf162;

struct __align__(8) bf16x4 { bf16 v[4]; };

__device__ __forceinline__ float b2f(bf16 h) { return __bfloat162float(h); }
__device__ __forceinline__ bf16 f2b(float f) { return __float2bfloat16(f); }

// ---------------------------------------------------------------------------
// Kernel 1: out[c][n] = sum_i W[c][i] * X[i][n] + bias[c]   (per batch)
// fp32 compute, bf16 output. 128x128 tile, 8x8 per thread (split 4+4).
// ---------------------------------------------------------------------------
__global__ __launch_bounds__(256) void proj_kernel(
    const float* __restrict__ X, const float* __restrict__ W,
    const float* __restrict__ bias, bf16* __restrict__ out)
{
    __shared__ float As[16][132];   // As[kk][c_local] (transposed store)
    __shared__ float Bs[16][132];   // Bs[kk][n_local]

    const int b  = blockIdx.z;
    const int n0 = blockIdx.x * 128;
    const int c0 = blockIdx.y * 128;
    const int tid = threadIdx.x;
    const int tx = tid & 15, ty = tid >> 4;
    const float* Xb = X + (size_t)b * CCH * NSEQ;
    bf16* outb = out + (size_t)b * CCH * NSEQ;

    float acc[8][8];
    #pragma unroll
    for (int i = 0; i < 8; ++i)
        #pragma unroll
        for (int j = 0; j < 8; ++j) acc[i][j] = 0.f;

    for (int kt = 0; kt < 16; ++kt) {
        const int k0 = kt * 16;
        #pragma unroll
        for (int e = tid; e < 2048; e += 256) {
            int r = e >> 4, kk = e & 15;
            As[kk][r] = W[(size_t)(c0 + r) * CCH + k0 + kk];
        }
        #pragma unroll
        for (int u = tid; u < 512; u += 256) {
            int kk = u >> 5, cq = u & 31;
            float4 val = *(const float4*)&Xb[(size_t)(k0 + kk) * NSEQ + n0 + cq * 4];
            *(float4*)&Bs[kk][cq * 4] = val;
        }
        __syncthreads();
        #pragma unroll
        for (int kk = 0; kk < 16; ++kk) {
            float4 a0 = *(float4*)&As[kk][ty * 4];
            float4 a1 = *(float4*)&As[kk][64 + ty * 4];
            float4 b0 = *(float4*)&Bs[kk][tx * 4];
            float4 b1 = *(float4*)&Bs[kk][64 + tx * 4];
            float a[8]  = {a0.x, a0.y, a0.z, a0.w, a1.x, a1.y, a1.z, a1.w};
            float bb[8] = {b0.x, b0.y, b0.z, b0.w, b1.x, b1.y, b1.z, b1.w};
            #pragma unroll
            for (int i = 0; i < 8; ++i)
                #pragma unroll
                for (int j = 0; j < 8; ++j)
                    acc[i][j] += a[i] * bb[j];
        }
        __syncthreads();
    }

    #pragma unroll
    for (int i = 0; i < 8; ++i) {
        int c = c0 + ((i < 4) ? (ty * 4 + i) : (64 + ty * 4 + (i - 4)));
        float bv = bias[c];
        #pragma unroll
        for (int g = 0; g < 2; ++g) {
            bf16x4 pk;
            #pragma unroll
            for (int j = 0; j < 4; ++j) pk.v[j] = f2b(acc[i][g * 4 + j] + bv);
            *(bf16x4*)&outb[(size_t)c * NSEQ + n0 + g * 64 + tx * 4] = pk;
        }
    }
}

// ---------------------------------------------------------------------------
// Kernel 2: flash attention. Per block: batch b, 64 query rows (n0..n0+63).
// Online softmax over m in tiles of 64. fp32 compute, bf16 q/k/v/av storage.
// Thread (tx,ty): S rows n = ty*4+r, cols m = tx*4+j;
//                 O rows n = ty*4+r, cols c = ch*64 + tx*4 + j (ch=0..3).
// ---------------------------------------------------------------------------
__global__ __launch_bounds__(256) void flash_kernel(
    const bf16* __restrict__ Q, const bf16* __restrict__ K,
    const bf16* __restrict__ V, bf16* __restrict__ AV)
{
    __shared__ float qs[16][64];    // [c_chunk][n_local]
    __shared__ float ks[16][64];    // [c_chunk][m_local]
    __shared__ float pts[64][68];   // [m_local][n_local]  (P after softmax)
    __shared__ float vts[16][260];  // [m_sub][c]          (V^T chunk)

    const int b  = blockIdx.y;
    const int n0 = blockIdx.x * 64;
    const int tid = threadIdx.x;
    const int tx = tid & 15, ty = tid >> 4;
    const size_t base = (size_t)b * CCH * NSEQ;

    float o[4][16];
    #pragma unroll
    for (int r = 0; r < 4; ++r)
        #pragma unroll
        for (int c = 0; c < 16; ++c) o[r][c] = 0.f;
    float mprev[4] = {-3e38f, -3e38f, -3e38f, -3e38f};
    float l[4] = {0.f, 0.f, 0.f, 0.f};

    for (int mt = 0; mt < 32; ++mt) {
        const int m0 = mt * 64;
        float s[4][4];
        #pragma unroll
        for (int r = 0; r < 4; ++r)
            #pragma unroll
            for (int j = 0; j < 4; ++j) s[r][j] = 0.f;

        // ---- scores: S = Q^T K over c in chunks of 16 ----
        for (int cc = 0; cc < 16; ++cc) {
            __syncthreads();
            #pragma unroll
            for (int u = tid; u < 512; u += 256) {
                int row = u >> 5, cq = u & 31;
                bf162 q2 = *(const bf162*)&Q[base + (size_t)(cc * 16 + row) * NSEQ + n0 + cq * 2];
                qs[row][cq * 2]     = b2f(q2.x);
                qs[row][cq * 2 + 1] = b2f(q2.y);
                bf162 k2 = *(const bf162*)&K[base + (size_t)(cc * 16 + row) * NSEQ + m0 + cq * 2];
                ks[row][cq * 2]     = b2f(k2.x);
                ks[row][cq * 2 + 1] = b2f(k2.y);
            }
            __syncthreads();
            #pragma unroll
            for (int i = 0; i < 16; ++i) {
                float4 q4 = *(float4*)&qs[i][ty * 4];
                float4 k4 = *(float4*)&ks[i][tx * 4];
                float qa[4] = {q4.x, q4.y, q4.z, q4.w};
                float ka[4] = {k4.x, k4.y, k4.z, k4.w};
                #pragma unroll
                for (int r = 0; r < 4; ++r)
                    #pragma unroll
                    for (int j = 0; j < 4; ++j)
                        s[r][j] += qa[r] * ka[j];
            }
        }

        // ---- online softmax update (per row; reduce across tx lanes) ----
        float alpha[4];
        #pragma unroll
        for (int r = 0; r < 4; ++r) {
            float mx = -3e38f;
            #pragma unroll
            for (int j = 0; j < 4; ++j) { s[r][j] *= 0.0625f; mx = fmaxf(mx, s[r][j]); }
            #pragma unroll
            for (int off = 1; off < 16; off <<= 1) mx = fmaxf(mx, __shfl_xor(mx, off));
            float nm = fmaxf(mprev[r], mx);
            alpha[r] = __expf(mprev[r] - nm);
            float sum = 0.f;
            #pragma unroll
            for (int j = 0; j < 4; ++j) { s[r][j] = __expf(s[r][j] - nm); sum += s[r][j]; }
            #pragma unroll
            for (int off = 1; off < 16; off <<= 1) sum += __shfl_xor(sum, off);
            l[r] = l[r] * alpha[r] + sum;
            mprev[r] = nm;
            #pragma unroll
            for (int c = 0; c < 16; ++c) o[r][c] *= alpha[r];
        }

        // ---- write P (transposed: pts[m][n]) ----
        #pragma unroll
        for (int j = 0; j < 4; ++j) {
            float4 col = make_float4(s[0][j], s[1][j], s[2][j], s[3][j]);
            *(float4*)&pts[tx * 4 + j][ty * 4] = col;
        }
        __syncthreads();

        // ---- AV: O += P V^T, m in sub-chunks of 16, all 256 channels ----
        for (int mc = 0; mc < 4; ++mc) {
            #pragma unroll
            for (int u = tid; u < 2048; u += 256) {
                int c = u >> 3, mq = u & 7;
                bf162 v2 = *(const bf162*)&V[base + (size_t)c * NSEQ + m0 + mc * 16 + mq * 2];
                vts[mq * 2][c]     = b2f(v2.x);
                vts[mq * 2 + 1][c] = b2f(v2.y);
            }
            __syncthreads();
            #pragma unroll
            for (int mm = 0; mm < 16; ++mm) {
                float4 p4 = *(float4*)&pts[mc * 16 + mm][ty * 4];
                float pa[4] = {p4.x, p4.y, p4.z, p4.w};
                #pragma unroll
                for (int ch = 0; ch < 4; ++ch) {
                    float4 v4 = *(float4*)&vts[mm][ch * 64 + tx * 4];
                    float va[4] = {v4.x, v4.y, v4.z, v4.w};
                    #pragma unroll
                    for (int r = 0; r < 4; ++r)
                        #pragma unroll
                        for (int j = 0; j < 4; ++j)
                            o[r][ch * 4 + j] += pa[r] * va[j];
                }
            }
            __syncthreads();
        }
    }

    // ---- epilogue: normalize by l, store av (bf16) ----
    float invl[4];
    #pragma unroll
    for (int r = 0; r < 4; ++r) invl[r] = 1.f / l[r];
    #pragma unroll
    for (int ch = 0; ch < 4; ++ch) {
        #pragma unroll
        for (int j = 0; j < 4; ++j) {
            int c = ch * 64 + tx * 4 + j;
            bf16x4 pk;
            #pragma unroll
            for (int r = 0; r < 4; ++r) pk.v[r] = f2b(o[r][ch * 4 + j] * invl[r]);
            *(bf16x4*)&AV[base + (size_t)c * NSEQ + n0 + ty * 4] = pk;
        }
    }
}

// ---------------------------------------------------------------------------
// Kernel 3: out[c][n] = x[c][n] + bias[c] + sum_i Wo[c][i] * av[i][n]
// av is bf16, everything else fp32. Same GEMM skeleton as proj_kernel.
// ---------------------------------------------------------------------------
__global__ __launch_bounds__(256) void outproj_kernel(
    const bf16* __restrict__ AVb, const float* __restrict__ W,
    const float* __restrict__ bias, const float* __restrict__ X,
    float* __restrict__ out)
{
    __shared__ float As[16][132];
    __shared__ float Bs[16][132];

    const int b  = blockIdx.z;
    const int n0 = blockIdx.x * 128;
    const int c0 = blockIdx.y * 128;
    const int tid = threadIdx.x;
    const int tx = tid & 15, ty = tid >> 4;
    const size_t base = (size_t)b * CCH * NSEQ;
    const float* Xb = X + base;
    float* outb = out + base;

    float acc[8][8];
    #pragma unroll
    for (int i = 0; i < 8; ++i)
        #pragma unroll
        for (int j = 0; j < 8; ++j) acc[i][j] = 0.f;

    for (int kt = 0; kt < 16; ++kt) {
        const int k0 = kt * 16;
        #pragma unroll
        for (int e = tid; e < 2048; e += 256) {
            int r = e >> 4, kk = e & 15;
            As[kk][r] = W[(size_t)(c0 + r) * CCH + k0 + kk];
        }
        #pragma unroll
        for (int u = tid; u < 512; u += 256) {
            int kk = u >> 5, cq = u & 31;
            const bf162* p = (const bf162*)&AVb[base + (size_t)(k0 + kk) * NSEQ + n0 + cq * 4];
            bf162 h0 = p[0], h1 = p[1];
            Bs[kk][cq * 4 + 0] = b2f(h0.x);
            Bs[kk][cq * 4 + 1] = b2f(h0.y);
            Bs[kk][cq * 4 + 2] = b2f(h1.x);
            Bs[kk][cq * 4 + 3] = b2f(h1.y);
        }
        __syncthreads();
        #pragma unroll
        for (int kk = 0; kk < 16; ++kk) {
            float4 a0 = *(float4*)&As[kk][ty * 4];
            float4 a1 = *(float4*)&As[kk][64 + ty * 4];
            float4 b0 = *(float4*)&Bs[kk][tx * 4];
            float4 b1 = *(float4*)&Bs[kk][64 + tx * 4];
            float a[8]  = {a0.x, a0.y, a0.z, a0.w, a1.x, a1.y, a1.z, a1.w};
            float bb[8] = {b0.x, b0.y, b0.z, b0.w, b1.x, b1.y, b1.z, b1.w};
            #pragma unroll
            for (int i = 0; i < 8; ++i)
                #pragma unroll
                for (int j = 0; j < 8; ++j)
                    acc[i][j] += a[i] * bb[j];
        }
        __syncthreads();
    }

    #pragma unroll
    for (int i = 0; i < 8; ++i) {
        int c = c0 + ((i < 4) ? (ty * 4 + i) : (64 + ty * 4 + (i - 4)));
        float bv = bias[c];
        #pragma unroll
        for (int g = 0; g < 2; ++g) {
            int n = n0 + g * 64 + tx * 4;
            float4 xr = *(const float4*)&Xb[(size_t)c * NSEQ + n];
            float4 ov;
            ov.x = acc[i][g * 4 + 0] + bv + xr.x;
            ov.y = acc[i][g * 4 + 1] + bv + xr.y;
            ov.z = acc[i][g * 4 + 2] + bv + xr.z;
            ov.w = acc[i][g * 4 + 3] + bv + xr.w;
            *(float4*)&outb[(size_t)c * NSEQ + n] = ov;
        }
    }
}

// ---------------------------------------------------------------------------
extern "C" void kernel_launch(void* const* d_in, const int* in_sizes, int n_in,
                              void* d_out, int out_size, void* d_ws, size_t ws_size,
                              hipStream_t stream) {
    (void)in_sizes; (void)n_in; (void)out_size; (void)ws_size;
    const float* x  = (const float*)d_in[0];
    const float* wq = (const float*)d_in[1];
    const float* bq = (const float*)d_in[2];
    const float* wk = (const float*)d_in[3];
    const float* bk = (const float*)d_in[4];
    const float* wv = (const float*)d_in[5];
    const float* bv = (const float*)d_in[6];
    const float* wo = (const float*)d_in[7];
    const float* bo = (const float*)d_in[8];
    float* out = (float*)d_out;

    const size_t T = (size_t)BATCH * CCH * NSEQ;  // 4,194,304 elements
    bf16* qb  = (bf16*)d_ws;
    bf16* kb  = qb + T;
    bf16* vb  = kb + T;
    bf16* avb = vb + T;      // total ws use: 4*T*2B = 33.6 MB

    dim3 blk(256);
    dim3 gp(16, 2, 8);       // n-tiles x c-tiles x batch

    proj_kernel<<<gp, blk, 0, stream>>>(x, wq, bq, qb);
    proj_kernel<<<gp, blk, 0, stream>>>(x, wk, bk, kb);
    proj_kernel<<<gp, blk, 0, stream>>>(x, wv, bv, vb);
    flash_kernel<<<dim3(32, 8), blk, 0, stream>>>(qb, kb, vb, avb);
    outproj_kernel<<<gp, blk, 0, stream>>>(avb, wo, bo, x, out);
}

// Round 2
// 249.015 us; speedup vs baseline: 5.2214x; 5.2214x over previous
//
#include <hip/hip_runtime.h>
#include <hip/hip_bf16.h>

#define CCH 256
#define NSEQ 2048
#define BATCH 8

typedef __hip_bfloat16 bf16;
typedef short s8v __attribute__((ext_vector_type(8)));   // 8 bf16 = 4 VGPR (MFMA A/B frag)
typedef float f4v __attribute__((ext_vector_type(4)));   // MFMA C/D frag

struct __align__(8) bf16x4 { bf16 v[4]; };

__device__ __forceinline__ float b2f(bf16 h) { return __bfloat162float(h); }
__device__ __forceinline__ bf16 f2b(float f) { return __float2bfloat16(f); }

#define MFMA16(a, b, c) __builtin_amdgcn_mfma_f32_16x16x32_bf16((a), (b), (c), 0, 0, 0)

// ---------------------------------------------------------------------------
// prep: z<8 -> transpose+cast x[b][c][n] fp32 -> xT[b][n][c] bf16 (64x64 tiles)
//       z==8 -> cast the four 256x256 weight matrices to bf16
// ---------------------------------------------------------------------------
__global__ __launch_bounds__(256) void prep_kernel(
    const float* __restrict__ x,
    const float* __restrict__ wq, const float* __restrict__ wk,
    const float* __restrict__ wv, const float* __restrict__ wo,
    bf16* __restrict__ xT, bf16* __restrict__ wqb, bf16* __restrict__ wkb,
    bf16* __restrict__ wvb, bf16* __restrict__ wob)
{
    const int tid = threadIdx.x;
    const int z = blockIdx.z;
    if (z == 8) {
        if (blockIdx.x >= 128) return;
        int base = (blockIdx.x * 256 + tid) * 8;      // 128*256*8 = 262144 = 4*65536
        int mat = base >> 16, off = base & 65535;
        const float* s = (mat == 0) ? wq : (mat == 1) ? wk : (mat == 2) ? wv : wo;
        bf16* d       = (mat == 0) ? wqb : (mat == 1) ? wkb : (mat == 2) ? wvb : wob;
        #pragma unroll
        for (int j = 0; j < 8; ++j) d[off + j] = f2b(s[off + j]);
        return;
    }
    __shared__ float tile[64][65];
    const int nt = blockIdx.x >> 2, ct = blockIdx.x & 3;
    const int c0 = ct * 64, n0 = nt * 64;
    const float* xb = x + (size_t)z * CCH * NSEQ;
    bf16* xTb = xT + (size_t)z * CCH * NSEQ;
    #pragma unroll
    for (int i = 0; i < 4; ++i) {
        int u = i * 256 + tid;
        int c = u >> 4, nq = u & 15;
        float4 v4 = *(const float4*)&xb[(size_t)(c0 + c) * NSEQ + n0 + nq * 4];
        tile[c][nq * 4 + 0] = v4.x; tile[c][nq * 4 + 1] = v4.y;
        tile[c][nq * 4 + 2] = v4.z; tile[c][nq * 4 + 3] = v4.w;
    }
    __syncthreads();
    #pragma unroll
    for (int i = 0; i < 4; ++i) {
        int u = i * 256 + tid;
        int n = u >> 4, cq = u & 15;
        bf16x4 pk;
        #pragma unroll
        for (int j = 0; j < 4; ++j) pk.v[j] = f2b(tile[cq * 4 + j][n]);
        *(bf16x4*)&xTb[(size_t)(n0 + n) * CCH + c0 + cq * 4] = pk;
    }
}

// ---------------------------------------------------------------------------
// proj_nt: outT[n][c] = (sum_i xT[n][i] * W[c][i] + bias[c]) * scale   (bf16)
// MFMA: A = xT rows (n), B = W rows (c). No LDS; W B-frags are L1-hot.
// Block: 128n x 64c, 4 waves split n (32n each). Grid (16, 4, 8).
// ---------------------------------------------------------------------------
__global__ __launch_bounds__(256) void proj_nt_kernel(
    const bf16* __restrict__ xT, const bf16* __restrict__ Wb,
    const float* __restrict__ bias, bf16* __restrict__ outT, float scale)
{
    const int b = blockIdx.z;
    const int n0 = blockIdx.x * 128;
    const int c0 = blockIdx.y * 64;
    const int tid = threadIdx.x;
    const int w = tid >> 6, lane = tid & 63;
    const int l15 = lane & 15, quad = lane >> 4;
    const bf16* xTb = xT + (size_t)b * CCH * NSEQ;

    const s8v* Arow0 = (const s8v*)(xTb + (size_t)(n0 + w * 32 + l15) * CCH);
    const s8v* Arow1 = (const s8v*)(xTb + (size_t)(n0 + w * 32 + 16 + l15) * CCH);
    const s8v* Brow[4];
    #pragma unroll
    for (int cs = 0; cs < 4; ++cs)
        Brow[cs] = (const s8v*)(Wb + (size_t)(c0 + cs * 16 + l15) * CCH);

    f4v acc[2][4] = {};
    #pragma unroll
    for (int t = 0; t < 8; ++t) {
        s8v a0 = Arow0[t * 4 + quad];
        s8v a1 = Arow1[t * 4 + quad];
        #pragma unroll
        for (int cs = 0; cs < 4; ++cs) {
            s8v bb = Brow[cs][t * 4 + quad];
            acc[0][cs] = MFMA16(a0, bb, acc[0][cs]);
            acc[1][cs] = MFMA16(a1, bb, acc[1][cs]);
        }
    }
    bf16* ob = outT + (size_t)b * CCH * NSEQ;
    #pragma unroll
    for (int cs = 0; cs < 4; ++cs) {
        float bv = bias[c0 + cs * 16 + l15];
        #pragma unroll
        for (int ns = 0; ns < 2; ++ns)
            #pragma unroll
            for (int r = 0; r < 4; ++r) {
                int n = n0 + w * 32 + ns * 16 + quad * 4 + r;
                ob[(size_t)n * CCH + c0 + cs * 16 + l15] =
                    f2b((acc[ns][cs][r] + bv) * scale);
            }
    }
}

// ---------------------------------------------------------------------------
// proj_cn: out[c][n] = sum_i W[c][i] * Bm[n][i] + bias[c]  (+x residual, fp32)
// MFMA: A = W rows (c, L1-hot), B = Bm rows (n). D: row=c, col=n.
// Block: 64c x 128n, 4 waves split n. Grid (16, 4, 8).
// outF!=null: fp32 out + residual (out-projection); else bf16 out (v).
// ---------------------------------------------------------------------------
__global__ __launch_bounds__(256) void proj_cn_kernel(
    const bf16* __restrict__ Bm, const bf16* __restrict__ Wb,
    const float* __restrict__ bias, const float* __restrict__ xres,
    bf16* __restrict__ outB, float* __restrict__ outF)
{
    const int b = blockIdx.z;
    const int n0 = blockIdx.x * 128;
    const int c0 = blockIdx.y * 64;
    const int tid = threadIdx.x;
    const int w = tid >> 6, lane = tid & 63;
    const int l15 = lane & 15, quad = lane >> 4;
    const bf16* Bmb = Bm + (size_t)b * CCH * NSEQ;

    const s8v* Arow[4];
    #pragma unroll
    for (int ms = 0; ms < 4; ++ms)
        Arow[ms] = (const s8v*)(Wb + (size_t)(c0 + ms * 16 + l15) * CCH);
    const s8v* Brow0 = (const s8v*)(Bmb + (size_t)(n0 + w * 32 + l15) * CCH);
    const s8v* Brow1 = (const s8v*)(Bmb + (size_t)(n0 + w * 32 + 16 + l15) * CCH);

    f4v acc[4][2] = {};
    #pragma unroll
    for (int t = 0; t < 8; ++t) {
        s8v b0 = Brow0[t * 4 + quad];
        s8v b1 = Brow1[t * 4 + quad];
        #pragma unroll
        for (int ms = 0; ms < 4; ++ms) {
            s8v a = Arow[ms][t * 4 + quad];
            acc[ms][0] = MFMA16(a, b0, acc[ms][0]);
            acc[ms][1] = MFMA16(a, b1, acc[ms][1]);
        }
    }
    const size_t obase = (size_t)b * CCH * NSEQ;
    #pragma unroll
    for (int ms = 0; ms < 4; ++ms)
        #pragma unroll
        for (int r = 0; r < 4; ++r) {
            int c = c0 + ms * 16 + quad * 4 + r;
            float bv = bias[c];
            #pragma unroll
            for (int ns = 0; ns < 2; ++ns) {
                size_t idx = obase + (size_t)c * NSEQ + n0 + w * 32 + ns * 16 + l15;
                float val = acc[ms][ns][r] + bv;
                if (outF) outF[idx] = val + xres[idx];
                else      outB[idx] = f2b(val);
            }
        }
}

// ---------------------------------------------------------------------------
// flash: per block: batch b, 64 query rows. m-loop in tiles of 64.
// Waves split n for QK^T (Q frags in registers), split c for PV (O in regs).
// LDS pads chosen so fragment reads spread 64 lanes evenly over 32 banks.
// ---------------------------------------------------------------------------
__global__ __launch_bounds__(256, 2) void flash_kernel(
    const bf16* __restrict__ qT, const bf16* __restrict__ kT,
    const bf16* __restrict__ V, bf16* __restrict__ avT)
{
    __shared__ bf16 Kt_s[64][264];   // [m][c]  stride 528B (132 dw %32 = 4)
    __shared__ bf16 Vs[256][72];     // [c][m]  stride 144B (36 dw %32 = 4)
    __shared__ bf16 Ps[64][72];      // [n][m]  stride 144B
    __shared__ float alpha_s[64];
    __shared__ float l_s[64];

    const int b = blockIdx.y;
    const int n0 = blockIdx.x * 64;
    const int tid = threadIdx.x;
    const int w = tid >> 6, lane = tid & 63;
    const int l15 = lane & 15, quad = lane >> 4;
    const size_t base = (size_t)b * CCH * NSEQ;
    const bf16* qTb = qT + base;     // [2048][256]
    const bf16* kTb = kT + base;     // [2048][256]
    const bf16* Vb  = V + base;      // [256][2048]

    // Q A-frags in registers: rows n0 + w*16 + l15, 8 k-steps of 32 channels
    s8v qf[8];
    {
        const s8v* qrow = (const s8v*)(qTb + (size_t)(n0 + w * 16 + l15) * CCH);
        #pragma unroll
        for (int t = 0; t < 8; ++t) qf[t] = qrow[t * 4 + quad];
    }

    f4v O[16] = {};                  // [ns*4+cs]: 64n x (wave's 64c)
    float mrow[4], lrow[4];
    #pragma unroll
    for (int r = 0; r < 4; ++r) { mrow[r] = -1e30f; lrow[r] = 0.f; }

    for (int mt = 0; mt < 32; ++mt) {
        const int m0 = mt * 64;
        __syncthreads();   // A: prev PV reads of Vs/Ps done; Kt free
        // stage K^T tile (64m x 256c, contiguous 32KB in global)
        {
            const s8v* ksrc = (const s8v*)(kTb + (size_t)m0 * CCH);
            #pragma unroll
            for (int i = 0; i < 8; ++i) {
                int u = i * 256 + tid;
                int m = u >> 5, cq = u & 31;
                *(s8v*)&Kt_s[m][cq * 8] = ksrc[u];
            }
            #pragma unroll
            for (int i = 0; i < 8; ++i) {
                int u = i * 256 + tid;
                int c = u >> 3, mq = u & 7;
                *(s8v*)&Vs[c][mq * 8] = *(const s8v*)&Vb[(size_t)c * NSEQ + m0 + mq * 8];
            }
        }
        __syncthreads();   // B: tiles ready

        // scores: wave w owns rows n = n0 + w*16 .. +15; S = 16n x 64m
        f4v S[4] = {};
        #pragma unroll
        for (int t = 0; t < 8; ++t)
            #pragma unroll
            for (int s = 0; s < 4; ++s) {
                s8v kf = *(const s8v*)&Kt_s[s * 16 + l15][t * 32 + quad * 8];
                S[s] = MFMA16(qf[t], kf, S[s]);
            }

        // online softmax per row (n local = quad*4 + r); reduce over l15
        float al[4];
        #pragma unroll
        for (int r = 0; r < 4; ++r) {
            float mx = fmaxf(fmaxf(S[0][r], S[1][r]), fmaxf(S[2][r], S[3][r]));
            #pragma unroll
            for (int off = 1; off < 16; off <<= 1) mx = fmaxf(mx, __shfl_xor(mx, off));
            float nm = fmaxf(mrow[r], mx);
            al[r] = __expf(mrow[r] - nm);
            mrow[r] = nm;
            float sum = 0.f;
            #pragma unroll
            for (int s = 0; s < 4; ++s) {
                float e = __expf(S[s][r] - nm);
                S[s][r] = e; sum += e;
            }
            #pragma unroll
            for (int off = 1; off < 16; off <<= 1) sum += __shfl_xor(sum, off);
            lrow[r] = lrow[r] * al[r] + sum;
        }
        // publish P (bf16) and alpha
        #pragma unroll
        for (int s = 0; s < 4; ++s)
            #pragma unroll
            for (int r = 0; r < 4; ++r)
                Ps[w * 16 + quad * 4 + r][s * 16 + l15] = f2b(S[s][r]);
        if (l15 == 0) {
            #pragma unroll
            for (int r = 0; r < 4; ++r) alpha_s[w * 16 + quad * 4 + r] = al[r];
        }
        __syncthreads();   // C: P/alpha ready for all waves

        // rescale O by alpha (per n-row)
        #pragma unroll
        for (int ns = 0; ns < 4; ++ns)
            #pragma unroll
            for (int r = 0; r < 4; ++r) {
                float a = alpha_s[ns * 16 + quad * 4 + r];
                #pragma unroll
                for (int cs = 0; cs < 4; ++cs) O[ns * 4 + cs][r] *= a;
            }

        // PV: O[n][c] += P[n][m] * V[c][m]; wave w owns c = w*64 .. +63
        #pragma unroll
        for (int ks = 0; ks < 2; ++ks) {
            s8v pa[4];
            #pragma unroll
            for (int ns = 0; ns < 4; ++ns)
                pa[ns] = *(const s8v*)&Ps[ns * 16 + l15][ks * 32 + quad * 8];
            #pragma unroll
            for (int cs = 0; cs < 4; ++cs) {
                s8v vf = *(const s8v*)&Vs[w * 64 + cs * 16 + l15][ks * 32 + quad * 8];
                #pragma unroll
                for (int ns = 0; ns < 4; ++ns)
                    O[ns * 4 + cs] = MFMA16(pa[ns], vf, O[ns * 4 + cs]);
            }
        }
    }

    // publish final l, normalize, store avT[n][c] bf16
    if (l15 == 0) {
        #pragma unroll
        for (int r = 0; r < 4; ++r) l_s[w * 16 + quad * 4 + r] = lrow[r];
    }
    __syncthreads();
    bf16* avb = avT + base;
    #pragma unroll
    for (int ns = 0; ns < 4; ++ns)
        #pragma unroll
        for (int r = 0; r < 4; ++r) {
            float il = 1.f / l_s[ns * 16 + quad * 4 + r];
            int n = n0 + ns * 16 + quad * 4 + r;
            #pragma unroll
            for (int cs = 0; cs < 4; ++cs)
                avb[(size_t)n * CCH + w * 64 + cs * 16 + l15] =
                    f2b(O[ns * 4 + cs][r] * il);
        }
}

// ---------------------------------------------------------------------------
extern "C" void kernel_launch(void* const* d_in, const int* in_sizes, int n_in,
                              void* d_out, int out_size, void* d_ws, size_t ws_size,
                              hipStream_t stream) {
    (void)in_sizes; (void)n_in; (void)out_size; (void)ws_size;
    const float* x  = (const float*)d_in[0];
    const float* wq = (const float*)d_in[1];
    const float* bq = (const float*)d_in[2];
    const float* wk = (const float*)d_in[3];
    const float* bk = (const float*)d_in[4];
    const float* wv = (const float*)d_in[5];
    const float* bv = (const float*)d_in[6];
    const float* wo = (const float*)d_in[7];
    const float* bo = (const float*)d_in[8];
    float* out = (float*)d_out;

    const size_t T = (size_t)BATCH * CCH * NSEQ;   // 4,194,304
    bf16* xT  = (bf16*)d_ws;
    bf16* qT  = xT + T;
    bf16* kT  = qT + T;
    bf16* v   = kT + T;
    bf16* avT = v + T;
    bf16* wqb = avT + T;
    bf16* wkb = wqb + 65536;
    bf16* wvb = wkb + 65536;
    bf16* wob = wvb + 65536;   // total ws: 5T*2 + 512KB = 42.5 MB

    dim3 blk(256);
    prep_kernel<<<dim3(128, 1, 9), blk, 0, stream>>>(x, wq, wk, wv, wo,
                                                     xT, wqb, wkb, wvb, wob);
    proj_nt_kernel<<<dim3(16, 4, 8), blk, 0, stream>>>(xT, wqb, bq, qT, 0.0625f);
    proj_nt_kernel<<<dim3(16, 4, 8), blk, 0, stream>>>(xT, wkb, bk, kT, 1.0f);
    proj_cn_kernel<<<dim3(16, 4, 8), blk, 0, stream>>>(xT, wvb, bv, nullptr, v, nullptr);
    flash_kernel<<<dim3(32, 8), blk, 0, stream>>>(qT, kT, v, avT);
    proj_cn_kernel<<<dim3(16, 4, 8), blk, 0, stream>>>(avT, wob, bo, x, nullptr, out);
}